// Round 1
// 317.357 us; speedup vs baseline: 1.0420x; 1.0420x over previous
//
#include <hip/hip_runtime.h>
#include <hip/hip_bf16.h>
#include <stddef.h>

// Problem constants
#define B_   64
#define C_   1024
#define CB_  256
#define T_   512
#define G_   8
#define N_   32768          // B_*T_
#define EPS_ 1e-5f

using short8  = __attribute__((ext_vector_type(8))) short;
using short4v = __attribute__((ext_vector_type(4))) short;
using f32x4   = __attribute__((ext_vector_type(4))) float;

__device__ __forceinline__ short f2bf(float f) {
    unsigned u = __float_as_uint(f);
    u += 0x7fffu + ((u >> 16) & 1u);   // RNE
    return (short)(u >> 16);
}

__device__ __forceinline__ float mish_f(float y) {
    // mish(y) = y * tanh(softplus(y)) = y * (u^2+2u)/(u^2+2u+2), u = e^y
    float u = __expf(fminf(y, 30.f));
    float w = u * u + 2.f * u;
    return y * (w / (w + 2.f));
}

// ---------------- Kernel 0: weights fp32 -> bf16 ----------------
// wd  -> wdb: plain [CB_][C_] bf16 (phase-A LDS staging layout, as before).
// wu  -> wut: MFMA-fragment-tiled bf16 so phase B reads A-fragments directly
//             from global, fully coalesced (1 KB per wave per fragment):
//   element (m,k) -> ((m/16)*8 + k/32)*512 + ((k/8)%4)*128 + (m%16)*8 + (k%8)
//   => lane (l16,q) reading rows m0+l16, k = kt*32+q*8.. is a contiguous
//      short8 at block_base + lane*8.
__global__ void prep_weights(const float* __restrict__ wd, const float* __restrict__ wu,
                             short* __restrict__ wdb, short* __restrict__ wut) {
    int i = blockIdx.x * 256 + threadIdx.x;
    if (i < CB_ * C_) {
        wdb[i] = f2bf(wd[i]);
        int m = i >> 8, k = i & 255;        // wu is [C_=1024][CB_=256]
        int idx = (((m >> 4) * 8 + (k >> 5)) << 9) + (((k >> 3) & 3) << 7)
                + ((m & 15) << 3) + (k & 7);
        wut[idx] = f2bf(wu[i]);
    }
}

// ---------------- Kernel 1: group stats -> per-(b,c) scale/shift ----------------
__global__ void stats_kernel(const float* __restrict__ x, const float* __restrict__ gamma,
                             const float* __restrict__ beta,
                             float* __restrict__ scaleW, float* __restrict__ shiftW) {
    const int tid = threadIdx.x;
    const int bg = blockIdx.x;
    const int b = bg >> 3, g = bg & 7;
    const float4* p = (const float4*)(x + ((size_t)b * C_ + g * 128) * T_);
    float s = 0.f, q = 0.f;
    for (int i = tid; i < 16384; i += 256) {
        float4 v = p[i];
        s += v.x + v.y + v.z + v.w;
        q += v.x * v.x + v.y * v.y + v.z * v.z + v.w * v.w;
    }
    for (int o = 32; o > 0; o >>= 1) {
        s += __shfl_down(s, o);
        q += __shfl_down(q, o);
    }
    __shared__ float red[8];
    __shared__ float mr[2];
    const int wid = tid >> 6, lane = tid & 63;
    if (lane == 0) { red[wid] = s; red[4 + wid] = q; }
    __syncthreads();
    if (tid == 0) {
        float S = red[0] + red[1] + red[2] + red[3];
        float Q = red[4] + red[5] + red[6] + red[7];
        float mean = S * (1.f / 65536.f);
        float var = Q * (1.f / 65536.f) - mean * mean;
        mr[0] = mean;
        mr[1] = rsqrtf(var + EPS_);
    }
    __syncthreads();
    float mean = mr[0], rstd = mr[1];
    if (tid < 128) {
        int c = g * 128 + tid;
        float sc = rstd * gamma[c];
        scaleW[b * C_ + c] = sc;
        shiftW[b * C_ + c] = beta[c] - mean * sc;
    }
}

// LDS row stride 40 bf16 (80 B = 20 dwords): ~2-way (free) for b128 fragment reads.
#define LDSTR 40
// mid-tile stride: 256 k + 8 pad = 264 shorts (528 B = 33*16 B): aligned b128,
// lane stride 132 dwords == 4 mod 32 banks -> 2-way (free).
#define MSTR  264

// ---------------- Kernel 2: FUSED  GN*scale/shift -> GEMM1 -> mish -> GEMM2 -> +resid ----
// One block per n-tile of 128 (grid = 256 = 1 block/CU), 512 threads = 8 waves.
// Phase A: (verified gemm1 structure) full M=256, K=1024, wave layout 4m x 2n.
// Epilogue A: +b_down, mish, bf16 -> LDS Ms[n][k] (128 x 264).
// Phase B: M=1024, K=256(all in LDS), N=128. A-fragments straight from global
//          (fragment-tiled wut, L2-resident) -> NO LDS staging, NO barriers.
__global__ __launch_bounds__(512, 2) void fused_adapter(
    const float* __restrict__ x, const short* __restrict__ wd,
    const float* __restrict__ b_down,
    const float* __restrict__ scaleW, const float* __restrict__ shiftW,
    const short* __restrict__ wut, const float* __restrict__ b_up,
    float* __restrict__ out) {
    __shared__ short As[256 * LDSTR];   // 20.0 KB
    __shared__ short Bs[128 * LDSTR];   // 10.0 KB
    __shared__ float sS[C_], sT[C_];    //  8.0 KB
    __shared__ short Ms[128 * MSTR];    // 66.0 KB   (total 104 KB, 1 block/CU)

    const int tid = threadIdx.x;
    const int n0 = blockIdx.x * 128;
    const int b  = n0 >> 9;
    const int t0 = n0 & 511;

    for (int i = tid; i < C_; i += 512) {
        sS[i] = scaleW[b * C_ + i];
        sT[i] = shiftW[b * C_ + i];
    }

    // A staging: 256 rows x 4 k-chunks(8) = 1024 short8; 512 thr -> 2 each
    const int a_kc = tid & 3;
    const int a_m  = tid >> 2;          // 0..127 (rows a_m, a_m+128)
    // B staging: 128 n x 32 k floats; thread: n=b_n, k octet b_kg*8
    const int b_n  = tid & 127;
    const int b_kg = tid >> 7;          // 0..3
    const int wid  = tid >> 6;
    const int lane = tid & 63;
    const int wm = wid >> 1, wn = wid & 1;   // wm 0..3, wn 0..1
    const int q = lane >> 4, l16 = lane & 15;

    f32x4 acc[4][4];
#pragma unroll
    for (int i = 0; i < 4; i++)
#pragma unroll
        for (int j = 0; j < 4; j++) acc[i][j] = 0.f;

    const float* xb = x + (size_t)b * C_ * T_ + t0;

    // ---- phase A prologue: global loads for kt=0 ----
    short8 a0, a1;
    float bv[8];
    {
        const short* src = wd + a_m * C_ + a_kc * 8;
        a0 = *(const short8*)src;
        a1 = *(const short8*)(src + 128 * C_);
        const float* xp = xb + (size_t)(b_kg * 8) * T_ + b_n;
#pragma unroll
        for (int i = 0; i < 8; i++) bv[i] = xp[(size_t)i * T_];
    }
    __syncthreads();   // sS/sT ready
    {
        *(short8*)&As[a_m * LDSTR + a_kc * 8] = a0;
        *(short8*)&As[(a_m + 128) * LDSTR + a_kc * 8] = a1;
        short8 v;
        const int kb = b_kg * 8;
#pragma unroll
        for (int i = 0; i < 8; i++) v[i] = f2bf(bv[i] * sS[kb + i] + sT[kb + i]);
        *(short8*)&Bs[b_n * LDSTR + kb] = v;
    }
    __syncthreads();

    for (int kt = 0; kt < 32; ++kt) {
        // prefetch kt+1
        if (kt < 31) {
            const int k1 = (kt + 1) * 32;
            const short* src = wd + a_m * C_ + k1 + a_kc * 8;
            a0 = *(const short8*)src;
            a1 = *(const short8*)(src + 128 * C_);
            const float* xp = xb + (size_t)(k1 + b_kg * 8) * T_ + b_n;
#pragma unroll
            for (int i = 0; i < 8; i++) bv[i] = xp[(size_t)i * T_];
        }
        // compute kt
        short8 af[4], bfr[4];
#pragma unroll
        for (int i = 0; i < 4; i++)
            af[i] = *(const short8*)&As[(wm * 64 + i * 16 + l16) * LDSTR + q * 8];
#pragma unroll
        for (int j = 0; j < 4; j++)
            bfr[j] = *(const short8*)&Bs[(wn * 64 + j * 16 + l16) * LDSTR + q * 8];
#pragma unroll
        for (int i = 0; i < 4; i++)
#pragma unroll
            for (int j = 0; j < 4; j++)
                acc[i][j] = __builtin_amdgcn_mfma_f32_16x16x32_bf16(af[i], bfr[j], acc[i][j], 0, 0, 0);
        __syncthreads();   // all waves done reading LDS tile kt
        if (kt < 31) {
            *(short8*)&As[a_m * LDSTR + a_kc * 8] = a0;
            *(short8*)&As[(a_m + 128) * LDSTR + a_kc * 8] = a1;
            short8 v;
            const int kb = (kt + 1) * 32 + b_kg * 8;
            const int kl = b_kg * 8;
#pragma unroll
            for (int i = 0; i < 8; i++) v[i] = f2bf(bv[i] * sS[kb + i] + sT[kb + i]);
            *(short8*)&Bs[b_n * LDSTR + kl] = v;
        }
        __syncthreads();
    }

    // ---- epilogue A: + b_down, mish, bf16 -> Ms[n][k]  (k = Cb index) ----
#pragma unroll
    for (int i = 0; i < 4; i++) {
        const int o_b = wm * 64 + i * 16 + q * 4;
        const float bd0 = b_down[o_b];
        const float bd1 = b_down[o_b + 1];
        const float bd2 = b_down[o_b + 2];
        const float bd3 = b_down[o_b + 3];
#pragma unroll
        for (int j = 0; j < 4; j++) {
            const int nl = wn * 64 + j * 16 + l16;
            short4v v;
            v[0] = f2bf(mish_f(acc[i][j][0] + bd0));
            v[1] = f2bf(mish_f(acc[i][j][1] + bd1));
            v[2] = f2bf(mish_f(acc[i][j][2] + bd2));
            v[3] = f2bf(mish_f(acc[i][j][3] + bd3));
            *(short4v*)&Ms[nl * MSTR + o_b] = v;
        }
    }
    __syncthreads();   // Ms fully written

    // ---- phase B: out[c, ttile] = wu[c,:] . Ms[:, n] + b_up + resid ----
    // Each wave owns 64 m-rows x 128 n per half; 2 halves -> M=1024.
#pragma unroll 1
    for (int half = 0; half < 2; ++half) {
        f32x4 a2[4][8];
#pragma unroll
        for (int i = 0; i < 4; i++)
#pragma unroll
            for (int j = 0; j < 8; j++) a2[i][j] = 0.f;

        const int mbb = half * 32 + wid * 4;     // m-tile-of-16 base index
#pragma unroll 2
        for (int kt = 0; kt < 8; ++kt) {
            short8 af[4], bf2[8];
#pragma unroll
            for (int i = 0; i < 4; i++)
                af[i] = *(const short8*)(wut + ((size_t)((mbb + i) * 8 + kt) << 9) + lane * 8);
#pragma unroll
            for (int j = 0; j < 8; j++)
                bf2[j] = *(const short8*)&Ms[(j * 16 + l16) * MSTR + kt * 32 + q * 8];
#pragma unroll
            for (int i = 0; i < 4; i++)
#pragma unroll
                for (int j = 0; j < 8; j++)
                    a2[i][j] = __builtin_amdgcn_mfma_f32_16x16x32_bf16(af[i], bf2[j], a2[i][j], 0, 0, 0);
        }

        // epilogue B: + b_up[c] + x residual, fp32 store
#pragma unroll
        for (int i = 0; i < 4; i++) {
            const int c_b = half * 512 + wid * 64 + i * 16 + q * 4;
            const float bu0 = b_up[c_b];
            const float bu1 = b_up[c_b + 1];
            const float bu2 = b_up[c_b + 2];
            const float bu3 = b_up[c_b + 3];
#pragma unroll
            for (int j = 0; j < 8; j++) {
                const int tt = t0 + j * 16 + l16;
                const size_t gi = ((size_t)b * C_ + c_b) * T_ + tt;
                out[gi]              = a2[i][j][0] + bu0 + x[gi];
                out[gi + T_]         = a2[i][j][1] + bu1 + x[gi + T_];
                out[gi + 2 * T_]     = a2[i][j][2] + bu2 + x[gi + 2 * T_];
                out[gi + 3 * T_]     = a2[i][j][3] + bu3 + x[gi + 3 * T_];
            }
        }
    }
}

// ---------------- Launch ----------------
extern "C" void kernel_launch(void* const* d_in, const int* in_sizes, int n_in,
                              void* d_out, int out_size, void* d_ws, size_t ws_size,
                              hipStream_t stream) {
    const float* x      = (const float*)d_in[0];
    const float* gamma  = (const float*)d_in[1];
    const float* beta   = (const float*)d_in[2];
    const float* w_down = (const float*)d_in[3];
    const float* b_down = (const float*)d_in[4];
    const float* w_up   = (const float*)d_in[5];
    const float* b_up   = (const float*)d_in[6];
    float* out = (float*)d_out;

    float* scaleW = (float*)d_ws;                       // B_*C_ floats
    float* shiftW = scaleW + B_ * C_;                   // B_*C_ floats
    short* wdb    = (short*)(shiftW + B_ * C_);         // CB_*C_ bf16
    short* wut    = wdb + CB_ * C_;                     // C_*CB_ bf16 (fragment-tiled)

    prep_weights<<<dim3((CB_ * C_ + 255) / 256), 256, 0, stream>>>(w_down, w_up, wdb, wut);
    stats_kernel<<<dim3(B_ * G_), 256, 0, stream>>>(x, gamma, beta, scaleW, shiftW);
    fused_adapter<<<dim3(N_ / 128), 512, 0, stream>>>(x, wdb, b_down, scaleW, shiftW,
                                                      wut, b_up, out);
}